// Round 13
// baseline (242.854 us; speedup 1.0000x reference)
//
#include <hip/hip_runtime.h>
#include <hip/hip_bf16.h>

#define S_ 4096
#define D_ 1024
#define H_ 16
#define DK_ 64
#define DV_ 64

typedef short bf16x8 __attribute__((ext_vector_type(8)));
typedef short bf16x4 __attribute__((ext_vector_type(4)));
typedef float floatx4 __attribute__((ext_vector_type(4)));
using bf16 = __hip_bfloat16;

#define MFMA16(a, b, c) __builtin_amdgcn_mfma_f32_16x16x32_bf16(a, b, c, 0, 0, 0)

#if __has_builtin(__builtin_amdgcn_exp2f)
#define EXP2(x) __builtin_amdgcn_exp2f(x)
#else
#define EXP2(x) exp2f(x)
#endif

// async global->LDS, 16B per lane. lds ptr wave-uniform; HW adds lane*16.
__device__ __forceinline__ void stage16(const void* g, void* l) {
    __builtin_amdgcn_global_load_lds(
        (const __attribute__((address_space(1))) void*)g,
        (__attribute__((address_space(3))) void*)l, 16, 0, 0);
}

// bf16x8 fragment from a swizzled [rows][64] LDS tile (row = 8 chunks of 16B).
__device__ __forceinline__ bf16x8 ldsfrag(const bf16* base, int row, int chunk) {
    return *(const bf16x8*)(base + row * 64 + (((chunk ^ (row & 7))) << 3));
}
// bf16x8 fragment from a swizzled [rows][32] LDS tile (row = 4 chunks of 16B).
__device__ __forceinline__ bf16x8 ldsfrag32(const bf16* base, int row, int chunk) {
    return *(const bf16x8*)(base + row * 32 + (((chunk ^ (row & 3))) << 3));
}

__device__ __forceinline__ unsigned short bfbits(float f) {
    union { bf16 h; unsigned short u; } c; c.h = __float2bfloat16(f); return c.u;
}
__device__ __forceinline__ float bf2f(bf16 h) { return __bfloat162float(h); }

// TRUNCATING pack of two fp32 -> bf16x2 in ONE v_perm_b32.
// Safe for softmax P (uniform trunc bias cancels in sum-normalization) and
// for already-normalized outputs (error < 1 ulp bf16 = within budget).
__device__ __forceinline__ unsigned int pktrunc(float lo, float hi) {
    union { float f; unsigned int u; } a, b;
    a.f = hi; b.f = lo;
    return __builtin_amdgcn_perm(a.u, b.u, 0x07060302u);
}

// ---------------------------------------------------------------------------
// prep (merged): [0,2048) cvt_x | [2048,2816) tr_qkv | [2816,3072) tr_wc
// ---------------------------------------------------------------------------
__global__ __launch_bounds__(256)
void prep(const float* __restrict__ x, const float* __restrict__ Wq,
          const float* __restrict__ Wk, const float* __restrict__ Wv,
          const float* __restrict__ Wc,
          bf16* __restrict__ xb, bf16* __restrict__ Wt, bf16* __restrict__ Wct)
{
    __shared__ float ls[64][65];
    const int bx = blockIdx.x, t = threadIdx.x;

    if (bx < 2048) {                       // ---- x fp32 -> bf16
        int i = bx * 2048 + t * 8;
        float4 a = *(const float4*)(x + i);
        float4 b = *(const float4*)(x + i + 4);
        ushort4 lo, hi;
        lo.x = bfbits(a.x); lo.y = bfbits(a.y); lo.z = bfbits(a.z); lo.w = bfbits(a.w);
        hi.x = bfbits(b.x); hi.y = bfbits(b.y); hi.z = bfbits(b.z); hi.w = bfbits(b.w);
        *(ushort4*)(xb + i) = lo;
        *(ushort4*)(xb + i + 4) = hi;
        return;
    }
    if (bx < 2816) {                       // ---- Wq/Wk/Wv transpose+cvt (+scale on Wq)
        const int idx = bx - 2048;
        const int z = idx >> 4, which = z >> 4, h = z & 15;
        const float* s = (which == 0 ? Wq : which == 1 ? Wk : Wv) + (size_t)h * D_ * 64;
        bf16* d = Wt + ((size_t)which * 1024 + h * 64) * D_;
        const float scale = (which == 0) ? 0.125f * 1.44269504088896340736f : 1.0f;
        const int r0 = (idx & 15) * 64;
        {
            int r = t >> 2, cseg = (t & 3) * 16;
            const float* sp = s + (size_t)(r0 + r) * 64 + cseg;
            #pragma unroll
            for (int i = 0; i < 16; i += 4) {
                float4 v = *(const float4*)(sp + i);
                ls[r][cseg + i + 0] = v.x; ls[r][cseg + i + 1] = v.y;
                ls[r][cseg + i + 2] = v.z; ls[r][cseg + i + 3] = v.w;
            }
        }
        __syncthreads();
        {
            int c = t >> 2, rseg = (t & 3) * 16;
            bf16* dp = d + (size_t)c * D_ + r0 + rseg;
            #pragma unroll
            for (int i = 0; i < 16; i++) dp[i] = __float2bfloat16(ls[rseg + i][c] * scale);
        }
        return;
    }
    {                                      // ---- Wc transpose+cvt
        const int idx = bx - 2816;
        const int r0 = (idx & 15) * 64, c0 = (idx >> 4) * 64;
        {
            int r = t >> 2, cseg = (t & 3) * 16;
            const float* sp = Wc + (size_t)(r0 + r) * D_ + c0 + cseg;
            #pragma unroll
            for (int i = 0; i < 16; i += 4) {
                float4 v = *(const float4*)(sp + i);
                ls[r][cseg + i + 0] = v.x; ls[r][cseg + i + 1] = v.y;
                ls[r][cseg + i + 2] = v.z; ls[r][cseg + i + 3] = v.w;
            }
        }
        __syncthreads();
        {
            int c = t >> 2, rseg = (t & 3) * 16;
            bf16* dp = Wct + (size_t)(c0 + c) * D_ + r0 + rseg;
            #pragma unroll
            for (int i = 0; i < 16; i++) dp[i] = __float2bfloat16(ls[rseg + i][c]);
        }
    }
}

// ---------------------------------------------------------------------------
// Kernel 1: fused QKV GEMM, 128x128 tiles, BK=32, dbuf global_load_lds.
// LDS 32 KB. (R10/R12 version)
// ---------------------------------------------------------------------------
__global__ __launch_bounds__(256)
void qkv_gemm(const bf16* __restrict__ xb, const bf16* __restrict__ Wt,
              bf16* __restrict__ Qb, bf16* __restrict__ Kb, bf16* __restrict__ Vtb)
{
    const int m0 = blockIdx.x * 128;
    const int n0 = blockIdx.y * 128;
    __shared__ __align__(16) bf16 xa[2][128 * 32];    // 8 KB each buf
    __shared__ __align__(16) bf16 wb2[2][128 * 32];

    const int t = threadIdx.x, lane = t & 63, w = t >> 6;
    const int l15 = lane & 15, quad = lane >> 4;

    auto stage_a = [&](int buf, int kk) {
        #pragma unroll
        for (int j = 0; j < 2; j++) {
            int row = j * 64 + (t >> 2);
            int ch  = (t & 3) ^ (row & 3);
            stage16((const char*)xb + ((size_t)(m0 + row) * D_ + kk) * 2 + ch * 16,
                    (char*)&xa[buf][0] + (j * 4 + w) * 1024);
        }
    };
    auto stage_b = [&](int buf, int kk) {
        #pragma unroll
        for (int j = 0; j < 2; j++) {
            int row = j * 64 + (t >> 2);
            int ch  = (t & 3) ^ (row & 3);
            stage16((const char*)Wt + ((size_t)(n0 + row) * D_ + kk) * 2 + ch * 16,
                    (char*)&wb2[buf][0] + (j * 4 + w) * 1024);
        }
    };

    const floatx4 fz = {0.f, 0.f, 0.f, 0.f};
    floatx4 acc[2][8];
    #pragma unroll
    for (int mt = 0; mt < 2; mt++)
        #pragma unroll
        for (int nt = 0; nt < 8; nt++) acc[mt][nt] = fz;

    stage_a(0, 0); stage_b(0, 0);
    for (int kt = 0; kt < 32; kt++) {
        int cur = kt & 1;
        __syncthreads();
        if (kt < 31) { stage_a(cur ^ 1, (kt + 1) * 32); stage_b(cur ^ 1, (kt + 1) * 32); }
        bf16x8 a0 = ldsfrag32(&xa[cur][0], w * 32 + l15,      quad);
        bf16x8 a1 = ldsfrag32(&xa[cur][0], w * 32 + 16 + l15, quad);
        #pragma unroll
        for (int nt = 0; nt < 8; nt++) {
            bf16x8 b = ldsfrag32(&wb2[cur][0], nt * 16 + l15, quad);
            acc[0][nt] = MFMA16(a0, b, acc[0][nt]);
            acc[1][nt] = MFMA16(a1, b, acc[1][nt]);
        }
    }

    const int which = n0 >> 10;            // uniform per block
    #pragma unroll
    for (int nt = 0; nt < 8; nt++) {
        int n = n0 + nt * 16 + l15;
        int hh = (n >> 6) & 15, col = n & 63;
        #pragma unroll
        for (int mt = 0; mt < 2; mt++)
            #pragma unroll
            for (int r = 0; r < 4; r++) {
                int s = m0 + w * 32 + mt * 16 + quad * 4 + r;
                bf16 val = __float2bfloat16(acc[mt][nt][r]);
                if (which == 0)      Qb[((size_t)hh * S_ + s) * 64 + col] = val;
                else if (which == 1) Kb[((size_t)hh * S_ + s) * 64 + col] = val;
                else                 Vtb[((size_t)hh * 64 + col) * S_ + s] = val;
            }
    }
}

// ---------------------------------------------------------------------------
// Kernel 2: attention. R11 structure (no P round-trip, Oᵀ = Vᵀ·Pᵀ in-register,
// trunc packs) with two register-pressure cuts:
//  (a) 64-key tile processed as two 32-key HALVES (QK->exp2->PV per half):
//      peak live sc drops 32->16 fp32, pf 8->4 — fits arch VGPRs, no accvgpr
//      round-trips for the softmax values.
//  (b) loop-carried staging pointers: 4 per-lane global addresses computed
//      once, advanced by constant strides (K: +8192 B, V: +128 B per tile).
// Same LDS (32 KB), same barrier count, same math.
// ---------------------------------------------------------------------------
template<int NKT, bool FULL>
__global__ __attribute__((amdgpu_waves_per_eu(4, 4))) __launch_bounds__(256)
void attn(const bf16* __restrict__ Qb, const bf16* __restrict__ Kb,
          const bf16* __restrict__ Vtb, bf16* __restrict__ Cat,
          bf16* __restrict__ Opart, float* __restrict__ lpart)
{
    const int m0 = blockIdx.x * 128;
    const int h  = blockIdx.y;
    const int half = blockIdx.z;
    const int keybase = half * (NKT * 64);

    __shared__ __align__(16) bf16 ka[2][64 * 64];   // 8 KB/buf, swizzled [key][dk]
    __shared__ __align__(16) bf16 vt[2][64 * 64];   // 8 KB/buf, swizzled [dv][key]

    const int t = threadIdx.x, lane = t & 63, w = t >> 6;
    const int l15 = lane & 15, quad = lane >> 4;

    // ---- loop-carried staging pointers (computed once) ----
    const int c0 = (0 * 4 + w) * 64 + lane;        // j=0 chunk id
    const int c1 = (1 * 4 + w) * 64 + lane;        // j=1 chunk id
    const int row0 = c0 >> 3, ch0 = (c0 & 7) ^ (row0 & 7);
    const int row1 = c1 >> 3, ch1 = (c1 & 7) ^ (row1 & 7);
    const char* kp0 = (const char*)(Kb + ((size_t)h * S_ + keybase) * 64)
                      + row0 * 128 + ch0 * 16;
    const char* kp1 = (const char*)(Kb + ((size_t)h * S_ + keybase) * 64)
                      + row1 * 128 + ch1 * 16;
    const char* vp0 = (const char*)(Vtb + (size_t)h * 64 * S_ + keybase)
                      + (size_t)row0 * (S_ * 2) + ch0 * 16;
    const char* vp1 = (const char*)(Vtb + (size_t)h * 64 * S_ + keybase)
                      + (size_t)row1 * (S_ * 2) + ch1 * 16;

    auto stage_kv = [&](int buf) {
        stage16(kp0, (char*)&ka[buf][0] + (0 * 4 + w) * 1024);
        stage16(kp1, (char*)&ka[buf][0] + (1 * 4 + w) * 1024);
        stage16(vp0, (char*)&vt[buf][0] + (0 * 4 + w) * 1024);
        stage16(vp1, (char*)&vt[buf][0] + (1 * 4 + w) * 1024);
        kp0 += 64 * 128;   // next 64 keys (K rows)
        kp1 += 64 * 128;
        vp0 += 64 * 2;     // next 64 keys along V^T row
        vp1 += 64 * 2;
    };

    // Q fragments, loop-invariant, straight from global (B-side of K·Qᵀ)
    bf16x8 qf[2][2];
    #pragma unroll
    for (int nq = 0; nq < 2; nq++)
        #pragma unroll
        for (int ks = 0; ks < 2; ks++)
            qf[nq][ks] = *(const bf16x8*)(Qb +
                ((size_t)h * S_ + m0 + w * 32 + nq * 16 + l15) * 64 + ks * 32 + quad * 8);

    const floatx4 fz = {0.f, 0.f, 0.f, 0.f};
    floatx4 acc[2][4];          // acc[nq][nt]: Oᵀ[dv=nt*16+quad*4+r][q=l15 of nq-tile]
    float rs[2] = {0.f, 0.f};
    #pragma unroll
    for (int nq = 0; nq < 2; nq++)
        #pragma unroll
        for (int nt = 0; nt < 4; nt++) acc[nq][nt] = fz;

    stage_kv(0);
    __syncthreads();

    for (int kt = 0; kt < NKT; kt++) {
        const int cur = kt & 1;
        if (kt + 1 < NKT) stage_kv(cur ^ 1);

        #pragma unroll
        for (int hf = 0; hf < 2; hf++) {   // two 32-key halves (key groups 2hf, 2hf+1)
            // Sᵀ[key][q] = K·Qᵀ for this half
            floatx4 sc[2][2];
            #pragma unroll
            for (int mk = 0; mk < 2; mk++)
                #pragma unroll
                for (int nq = 0; nq < 2; nq++) sc[mk][nq] = fz;
            #pragma unroll
            for (int ks = 0; ks < 2; ks++) {
                bf16x8 af0 = ldsfrag(&ka[cur][0], (hf * 2 + 0) * 16 + l15, ks * 4 + quad);
                bf16x8 af1 = ldsfrag(&ka[cur][0], (hf * 2 + 1) * 16 + l15, ks * 4 + quad);
                #pragma unroll
                for (int nq = 0; nq < 2; nq++) {
                    sc[0][nq] = MFMA16(af0, qf[nq][ks], sc[0][nq]);
                    sc[1][nq] = MFMA16(af1, qf[nq][ks], sc[1][nq]);
                }
            }

            // p = exp2(s); per-lane partial row sums; trunc packs
            union bf4u { bf16x4 v; unsigned int u[2]; };
            bf4u pf[2][2];
            #pragma unroll
            for (int mk = 0; mk < 2; mk++)
                #pragma unroll
                for (int nq = 0; nq < 2; nq++) {
                    float p0 = EXP2(sc[mk][nq][0]);
                    float p1 = EXP2(sc[mk][nq][1]);
                    float p2 = EXP2(sc[mk][nq][2]);
                    float p3 = EXP2(sc[mk][nq][3]);
                    rs[nq] += (p0 + p1) + (p2 + p3);
                    pf[mk][nq].u[0] = pktrunc(p0, p1);
                    pf[mk][nq].u[1] = pktrunc(p2, p3);
                }

            // Oᵀ += Vᵀ·Pᵀ for this half (32 keys per MFMA, k-map = groups 2hf,2hf+1)
            union { bf16x8 v8; bf16x4 v4[2]; } b8[2];
            #pragma unroll
            for (int nq = 0; nq < 2; nq++) {
                b8[nq].v4[0] = pf[0][nq].v;
                b8[nq].v4[1] = pf[1][nq].v;
            }
            #pragma unroll
            for (int nt = 0; nt < 4; nt++) {
                const char* vb = (const char*)&vt[cur][0]
                               + (nt * 16 + l15) * 128 + (quad & 1) * 8;
                const int r7 = l15 & 7;            // row&7 for swizzle
                union { bf16x8 v8; bf16x4 v4[2]; } a8;
                a8.v4[0] = *(const bf16x4*)(vb + (((4 * hf +     (quad >> 1)) ^ r7) << 4));
                a8.v4[1] = *(const bf16x4*)(vb + (((4 * hf + 2 + (quad >> 1)) ^ r7) << 4));
                #pragma unroll
                for (int nq = 0; nq < 2; nq++)
                    acc[nq][nt] = MFMA16(a8.v8, b8[nq].v8, acc[nq][nt]);
            }
        }
        __syncthreads();   // staging(next) landed; all waves done with cur
    }

    // full row sums: q = l15, reduce across the 4 quads (lanes ±16, ±32)
    #pragma unroll
    for (int nq = 0; nq < 2; nq++) {
        rs[nq] += __shfl_xor(rs[nq], 16);
        rs[nq] += __shfl_xor(rs[nq], 32);
    }

    if (FULL) {
        #pragma unroll
        for (int nq = 0; nq < 2; nq++) {
            float inv = 1.0f / rs[nq];
            int q = m0 + w * 32 + nq * 16 + l15;
            #pragma unroll
            for (int nt = 0; nt < 4; nt++) {
                uint2 o;
                o.x = pktrunc(acc[nq][nt][0] * inv, acc[nq][nt][1] * inv);
                o.y = pktrunc(acc[nq][nt][2] * inv, acc[nq][nt][3] * inv);
                *(uint2*)(Cat + (size_t)q * (H_ * DV_) + h * 64 + nt * 16 + quad * 4) = o;
            }
        }
    } else {
        const size_t plane = (size_t)(half * H_ + h) * S_;
        #pragma unroll
        for (int nq = 0; nq < 2; nq++) {
            int q = m0 + w * 32 + nq * 16 + l15;
            #pragma unroll
            for (int nt = 0; nt < 4; nt++) {
                uint2 o;
                o.x = pktrunc(acc[nq][nt][0], acc[nq][nt][1]);
                o.y = pktrunc(acc[nq][nt][2], acc[nq][nt][3]);
                *(uint2*)(Opart + (plane + q) * 64 + nt * 16 + quad * 4) = o;
            }
            if (quad == 0) lpart[plane + q] = rs[nq];
        }
    }
}

// ---------------------------------------------------------------------------
// Kernel 2b: combine bf16 key-split partials -> Cat bf16
// ---------------------------------------------------------------------------
__global__ __launch_bounds__(256)
void combine(const bf16* __restrict__ Opart, const float* __restrict__ lpart,
             bf16* __restrict__ Cat)
{
    const int h = blockIdx.y;
    const int off = (blockIdx.x * 256 + threadIdx.x) * 8;   // within [S*64]
    const int s = off >> 6, dv = off & 63;
    union { bf16x8 v; bf16 e[8]; } o0, o1;
    o0.v = *(const bf16x8*)(Opart + (size_t)h * S_ * 64 + off);
    o1.v = *(const bf16x8*)(Opart + (size_t)(H_ + h) * S_ * 64 + off);
    float inv = 1.0f / (lpart[(size_t)h * S_ + s] + lpart[(size_t)(H_ + h) * S_ + s]);
    uint4 o;
    o.x = pktrunc((bf2f(o0.e[0]) + bf2f(o1.e[0])) * inv, (bf2f(o0.e[1]) + bf2f(o1.e[1])) * inv);
    o.y = pktrunc((bf2f(o0.e[2]) + bf2f(o1.e[2])) * inv, (bf2f(o0.e[3]) + bf2f(o1.e[3])) * inv);
    o.z = pktrunc((bf2f(o0.e[4]) + bf2f(o1.e[4])) * inv, (bf2f(o0.e[5]) + bf2f(o1.e[5])) * inv);
    o.w = pktrunc((bf2f(o0.e[6]) + bf2f(o1.e[6])) * inv, (bf2f(o0.e[7]) + bf2f(o1.e[7])) * inv);
    *(uint4*)(Cat + (size_t)s * (H_ * DV_) + h * 64 + dv) = o;
}

// ---------------------------------------------------------------------------
// Kernel 3: output projection, 128x64 tiles, BK=32, dbuf staging. LDS 24 KB.
// ---------------------------------------------------------------------------
__global__ __launch_bounds__(256)
void out_proj(const bf16* __restrict__ Cat, const bf16* __restrict__ Wct,
              const float* __restrict__ bc, float* __restrict__ out)
{
    const int m0 = blockIdx.x * 128;
    const int n0 = blockIdx.y * 64;
    __shared__ __align__(16) bf16 ca[2][128 * 32];   // 8 KB/buf
    __shared__ __align__(16) bf16 wb2[2][64 * 32];   // 4 KB/buf

    const int t = threadIdx.x, lane = t & 63, w = t >> 6;
    const int l15 = lane & 15, quad = lane >> 4;

    auto stage_a = [&](int buf, int kk) {
        #pragma unroll
        for (int j = 0; j < 2; j++) {
            int row = j * 64 + (t >> 2);
            int ch  = (t & 3) ^ (row & 3);
            stage16((const char*)Cat + ((size_t)(m0 + row) * D_ + kk) * 2 + ch * 16,
                    (char*)&ca[buf][0] + (j * 4 + w) * 1024);
        }
    };
    auto stage_b = [&](int buf, int kk) {
        int row = t >> 2;                   // 0..63
        int ch  = (t & 3) ^ (row & 3);
        stage16((const char*)Wct + ((size_t)(n0 + row) * D_ + kk) * 2 + ch * 16,
                (char*)&wb2[buf][0] + w * 1024);
    };

    const floatx4 fz = {0.f, 0.f, 0.f, 0.f};
    floatx4 acc[2][4];
    #pragma unroll
    for (int mt = 0; mt < 2; mt++)
        #pragma unroll
        for (int nt = 0; nt < 4; nt++) acc[mt][nt] = fz;

    stage_a(0, 0); stage_b(0, 0);
    for (int kt = 0; kt < 32; kt++) {
        int cur = kt & 1;
        __syncthreads();
        if (kt < 31) { stage_a(cur ^ 1, (kt + 1) * 32); stage_b(cur ^ 1, (kt + 1) * 32); }
        bf16x8 a0 = ldsfrag32(&ca[cur][0], w * 32 + l15,      quad);
        bf16x8 a1 = ldsfrag32(&ca[cur][0], w * 32 + 16 + l15, quad);
        #pragma unroll
        for (int nt = 0; nt < 4; nt++) {
            bf16x8 b = ldsfrag32(&wb2[cur][0], nt * 16 + l15, quad);
            acc[0][nt] = MFMA16(a0, b, acc[0][nt]);
            acc[1][nt] = MFMA16(a1, b, acc[1][nt]);
        }
    }

    #pragma unroll
    for (int nt = 0; nt < 4; nt++) {
        int col = n0 + nt * 16 + l15;
        float bias = bc[col];
        #pragma unroll
        for (int mt = 0; mt < 2; mt++)
            #pragma unroll
            for (int r = 0; r < 4; r++) {
                int row = m0 + w * 32 + mt * 16 + quad * 4 + r;
                out[(size_t)row * D_ + col] = acc[mt][nt][r] + bias;
            }
    }
}

extern "C" void kernel_launch(void* const* d_in, const int* in_sizes, int n_in,
                              void* d_out, int out_size, void* d_ws, size_t ws_size,
                              hipStream_t stream)
{
    const float* x  = (const float*)d_in[0];
    const float* Wq = (const float*)d_in[1];
    const float* Wk = (const float*)d_in[2];
    const float* Wv = (const float*)d_in[3];
    const float* Wc = (const float*)d_in[4];
    const float* bc = (const float*)d_in[5];
    float* out = (float*)d_out;

    bf16* xb  = (bf16*)d_ws;                          // [S][D] 8MB, aliased as Cat
    bf16* Cat = xb;
    bf16* Wt  = xb  + (size_t)S_ * D_;                // [3072][1024] 6MB
    bf16* Wct = Wt  + (size_t)3 * H_ * 64 * D_;       // [1024][1024] 2MB
    bf16* Qb  = Wct + (size_t)D_ * H_ * DV_;          // [H][S][64]  8MB
    bf16* Kb  = Qb  + (size_t)H_ * S_ * 64;           // [H][S][64]  8MB
    bf16* Vtb = Kb  + (size_t)H_ * S_ * 64;           // [H][64][S]  8MB
    bf16* Opart = Vtb + (size_t)H_ * 64 * S_;         // [2][H][S][64] bf16 16MB
    float* lpart = (float*)(Opart + (size_t)2 * H_ * S_ * 64);  // [2][H][S] 512KB

    const size_t need_split = (size_t)((char*)(lpart + (size_t)2 * H_ * S_) - (char*)d_ws);
    const bool split = ws_size >= need_split;

    prep<<<dim3(3072), 256, 0, stream>>>(x, Wq, Wk, Wv, Wc, xb, Wt, Wct);
    qkv_gemm<<<dim3(S_ / 128, 3072 / 128), 256, 0, stream>>>(xb, Wt, Qb, Kb, Vtb);

    if (split) {
        attn<32, false><<<dim3(S_ / 128, H_, 2), 256, 0, stream>>>(
            Qb, Kb, Vtb, Cat, Opart, lpart);
        combine<<<dim3(S_ * 64 / 2048, H_), 256, 0, stream>>>(Opart, lpart, Cat);
    } else {
        attn<64, true><<<dim3(S_ / 128, H_, 1), 256, 0, stream>>>(
            Qb, Kb, Vtb, Cat, Opart, lpart);
    }

    out_proj<<<dim3(S_ / 128, D_ / 64), 256, 0, stream>>>(Cat, Wct, bc, out);
}

// Round 14
// 234.185 us; speedup vs baseline: 1.0370x; 1.0370x over previous
//
#include <hip/hip_runtime.h>
#include <hip/hip_bf16.h>

#define S_ 4096
#define D_ 1024
#define H_ 16
#define DK_ 64
#define DV_ 64

typedef short bf16x8 __attribute__((ext_vector_type(8)));
typedef short bf16x4 __attribute__((ext_vector_type(4)));
typedef float floatx4 __attribute__((ext_vector_type(4)));
using bf16 = __hip_bfloat16;

#define MFMA16(a, b, c) __builtin_amdgcn_mfma_f32_16x16x32_bf16(a, b, c, 0, 0, 0)

#if __has_builtin(__builtin_amdgcn_exp2f)
#define EXP2(x) __builtin_amdgcn_exp2f(x)
#else
#define EXP2(x) exp2f(x)
#endif

// async global->LDS, 16B per lane. lds ptr wave-uniform; HW adds lane*16.
__device__ __forceinline__ void stage16(const void* g, void* l) {
    __builtin_amdgcn_global_load_lds(
        (const __attribute__((address_space(1))) void*)g,
        (__attribute__((address_space(3))) void*)l, 16, 0, 0);
}

// bf16x8 fragment from a swizzled [rows][64] LDS tile (row = 8 chunks of 16B).
__device__ __forceinline__ bf16x8 ldsfrag(const bf16* base, int row, int chunk) {
    return *(const bf16x8*)(base + row * 64 + (((chunk ^ (row & 7))) << 3));
}
// bf16x8 fragment from a swizzled [rows][32] LDS tile (row = 4 chunks of 16B).
__device__ __forceinline__ bf16x8 ldsfrag32(const bf16* base, int row, int chunk) {
    return *(const bf16x8*)(base + row * 32 + (((chunk ^ (row & 3))) << 3));
}

__device__ __forceinline__ unsigned short bfbits(float f) {
    union { bf16 h; unsigned short u; } c; c.h = __float2bfloat16(f); return c.u;
}
__device__ __forceinline__ float bf2f(bf16 h) { return __bfloat162float(h); }
// RNE pair pack (epilogue use — precision-preserving)
__device__ __forceinline__ unsigned int pkrne(float lo, float hi) {
    return (unsigned int)bfbits(lo) | ((unsigned int)bfbits(hi) << 16);
}

// TRUNCATING pack of two fp32 -> bf16x2 in ONE v_perm_b32.
// Safe for softmax P (uniform trunc bias cancels in sum-normalization) and
// for already-normalized outputs (error < 1 ulp bf16 = within budget).
__device__ __forceinline__ unsigned int pktrunc(float lo, float hi) {
    union { float f; unsigned int u; } a, b;
    a.f = hi; b.f = lo;
    return __builtin_amdgcn_perm(a.u, b.u, 0x07060302u);
}

// ---------------------------------------------------------------------------
// prep (merged): [0,2048) cvt_x | [2048,2816) tr_qkv | [2816,3072) tr_wc
// (R10/R12 version)
// ---------------------------------------------------------------------------
__global__ __launch_bounds__(256)
void prep(const float* __restrict__ x, const float* __restrict__ Wq,
          const float* __restrict__ Wk, const float* __restrict__ Wv,
          const float* __restrict__ Wc,
          bf16* __restrict__ xb, bf16* __restrict__ Wt, bf16* __restrict__ Wct)
{
    __shared__ float ls[64][65];
    const int bx = blockIdx.x, t = threadIdx.x;

    if (bx < 2048) {                       // ---- x fp32 -> bf16
        int i = bx * 2048 + t * 8;
        float4 a = *(const float4*)(x + i);
        float4 b = *(const float4*)(x + i + 4);
        ushort4 lo, hi;
        lo.x = bfbits(a.x); lo.y = bfbits(a.y); lo.z = bfbits(a.z); lo.w = bfbits(a.w);
        hi.x = bfbits(b.x); hi.y = bfbits(b.y); hi.z = bfbits(b.z); hi.w = bfbits(b.w);
        *(ushort4*)(xb + i) = lo;
        *(ushort4*)(xb + i + 4) = hi;
        return;
    }
    if (bx < 2816) {                       // ---- Wq/Wk/Wv transpose+cvt (+scale on Wq)
        const int idx = bx - 2048;
        const int z = idx >> 4, which = z >> 4, h = z & 15;
        const float* s = (which == 0 ? Wq : which == 1 ? Wk : Wv) + (size_t)h * D_ * 64;
        bf16* d = Wt + ((size_t)which * 1024 + h * 64) * D_;
        const float scale = (which == 0) ? 0.125f * 1.44269504088896340736f : 1.0f;
        const int r0 = (idx & 15) * 64;
        {
            int r = t >> 2, cseg = (t & 3) * 16;
            const float* sp = s + (size_t)(r0 + r) * 64 + cseg;
            #pragma unroll
            for (int i = 0; i < 16; i += 4) {
                float4 v = *(const float4*)(sp + i);
                ls[r][cseg + i + 0] = v.x; ls[r][cseg + i + 1] = v.y;
                ls[r][cseg + i + 2] = v.z; ls[r][cseg + i + 3] = v.w;
            }
        }
        __syncthreads();
        {
            int c = t >> 2, rseg = (t & 3) * 16;
            bf16* dp = d + (size_t)c * D_ + r0 + rseg;
            #pragma unroll
            for (int i = 0; i < 16; i++) dp[i] = __float2bfloat16(ls[rseg + i][c] * scale);
        }
        return;
    }
    {                                      // ---- Wc transpose+cvt
        const int idx = bx - 2816;
        const int r0 = (idx & 15) * 64, c0 = (idx >> 4) * 64;
        {
            int r = t >> 2, cseg = (t & 3) * 16;
            const float* sp = Wc + (size_t)(r0 + r) * D_ + c0 + cseg;
            #pragma unroll
            for (int i = 0; i < 16; i += 4) {
                float4 v = *(const float4*)(sp + i);
                ls[r][cseg + i + 0] = v.x; ls[r][cseg + i + 1] = v.y;
                ls[r][cseg + i + 2] = v.z; ls[r][cseg + i + 3] = v.w;
            }
        }
        __syncthreads();
        {
            int c = t >> 2, rseg = (t & 3) * 16;
            bf16* dp = Wct + (size_t)(c0 + c) * D_ + r0 + rseg;
            #pragma unroll
            for (int i = 0; i < 16; i++) dp[i] = __float2bfloat16(ls[rseg + i][c]);
        }
    }
}

// ---------------------------------------------------------------------------
// Kernel 1: fused QKV GEMM, 128x128 tiles, BK=32, dbuf global_load_lds.
// LDS 32 KB.  NEW epilogue scheme:
//  - Q/K blocks run the K-loop with SWAPPED MFMA operands (W-frag as A,
//    x-frag as B) -> C^T in registers: each reg-quad holds 4 consecutive
//    OUTPUT COLUMNS of one s-row -> 16 uint2 (8B) stores per thread.
//  - V blocks keep normal orientation: reg-quad = 4 consecutive s of one
//    dv row of Vtb[h][dv][S] -> 16 uint2 stores per thread.
// (was: 64 scalar 2B stores per thread — ~12.6M store instrs total)
// ---------------------------------------------------------------------------
__global__ __launch_bounds__(256)
void qkv_gemm(const bf16* __restrict__ xb, const bf16* __restrict__ Wt,
              bf16* __restrict__ Qb, bf16* __restrict__ Kb, bf16* __restrict__ Vtb)
{
    const int m0 = blockIdx.x * 128;
    const int n0 = blockIdx.y * 128;
    __shared__ __align__(16) bf16 xa[2][128 * 32];    // 8 KB each buf
    __shared__ __align__(16) bf16 wb2[2][128 * 32];

    const int t = threadIdx.x, lane = t & 63, w = t >> 6;
    const int l15 = lane & 15, quad = lane >> 4;

    auto stage_a = [&](int buf, int kk) {
        #pragma unroll
        for (int j = 0; j < 2; j++) {
            int row = j * 64 + (t >> 2);
            int ch  = (t & 3) ^ (row & 3);
            stage16((const char*)xb + ((size_t)(m0 + row) * D_ + kk) * 2 + ch * 16,
                    (char*)&xa[buf][0] + (j * 4 + w) * 1024);
        }
    };
    auto stage_b = [&](int buf, int kk) {
        #pragma unroll
        for (int j = 0; j < 2; j++) {
            int row = j * 64 + (t >> 2);
            int ch  = (t & 3) ^ (row & 3);
            stage16((const char*)Wt + ((size_t)(n0 + row) * D_ + kk) * 2 + ch * 16,
                    (char*)&wb2[buf][0] + (j * 4 + w) * 1024);
        }
    };

    const floatx4 fz = {0.f, 0.f, 0.f, 0.f};
    floatx4 acc[2][8];
    #pragma unroll
    for (int mt = 0; mt < 2; mt++)
        #pragma unroll
        for (int nt = 0; nt < 8; nt++) acc[mt][nt] = fz;

    const int which = n0 >> 10;            // uniform per block

    stage_a(0, 0); stage_b(0, 0);
    if (which != 2) {
        // ---- Q/K: swapped operands -> C^T regs ----
        for (int kt = 0; kt < 32; kt++) {
            int cur = kt & 1;
            __syncthreads();
            if (kt < 31) { stage_a(cur ^ 1, (kt + 1) * 32); stage_b(cur ^ 1, (kt + 1) * 32); }
            bf16x8 a0 = ldsfrag32(&xa[cur][0], w * 32 + l15,      quad);
            bf16x8 a1 = ldsfrag32(&xa[cur][0], w * 32 + 16 + l15, quad);
            #pragma unroll
            for (int nt = 0; nt < 8; nt++) {
                bf16x8 b = ldsfrag32(&wb2[cur][0], nt * 16 + l15, quad);
                acc[0][nt] = MFMA16(b, a0, acc[0][nt]);   // C^T: rows=n, cols=m
                acc[1][nt] = MFMA16(b, a1, acc[1][nt]);
            }
        }
        // epilogue: lane holds s = m0 + w*32 + mt*16 + l15 (col index),
        // n = n0 + nt*16 + quad*4 + r (row index) -> 4 consecutive cols per quad
        bf16* base = (which == 0) ? Qb : Kb;
        #pragma unroll
        for (int nt = 0; nt < 8; nt++) {
            int n  = n0 + nt * 16 + quad * 4;
            int hh = (n >> 6) & 15, col = n & 63;
            #pragma unroll
            for (int mt = 0; mt < 2; mt++) {
                int s = m0 + w * 32 + mt * 16 + l15;
                uint2 o;
                o.x = pkrne(acc[mt][nt][0], acc[mt][nt][1]);
                o.y = pkrne(acc[mt][nt][2], acc[mt][nt][3]);
                *(uint2*)(base + ((size_t)hh * S_ + s) * 64 + col) = o;
            }
        }
    } else {
        // ---- V: normal orientation -> reg-quad = 4 consecutive s ----
        for (int kt = 0; kt < 32; kt++) {
            int cur = kt & 1;
            __syncthreads();
            if (kt < 31) { stage_a(cur ^ 1, (kt + 1) * 32); stage_b(cur ^ 1, (kt + 1) * 32); }
            bf16x8 a0 = ldsfrag32(&xa[cur][0], w * 32 + l15,      quad);
            bf16x8 a1 = ldsfrag32(&xa[cur][0], w * 32 + 16 + l15, quad);
            #pragma unroll
            for (int nt = 0; nt < 8; nt++) {
                bf16x8 b = ldsfrag32(&wb2[cur][0], nt * 16 + l15, quad);
                acc[0][nt] = MFMA16(a0, b, acc[0][nt]);
                acc[1][nt] = MFMA16(a1, b, acc[1][nt]);
            }
        }
        #pragma unroll
        for (int nt = 0; nt < 8; nt++) {
            int n = n0 + nt * 16 + l15;
            int hh = (n >> 6) & 15, col = n & 63;
            #pragma unroll
            for (int mt = 0; mt < 2; mt++) {
                int s = m0 + w * 32 + mt * 16 + quad * 4;
                uint2 o;
                o.x = pkrne(acc[mt][nt][0], acc[mt][nt][1]);
                o.y = pkrne(acc[mt][nt][2], acc[mt][nt][3]);
                *(uint2*)(Vtb + ((size_t)hh * 64 + col) * S_ + s) = o;
            }
        }
    }
}

// ---------------------------------------------------------------------------
// Kernel 2: attention (R12 version exactly — measured best attn, 88.5-89 µs:
// no P round-trip, Oᵀ = Vᵀ·Pᵀ in-register, trunc packs,
// amdgpu_waves_per_eu(4,4)). LDS 32 KB -> 4 blocks/CU.
// ---------------------------------------------------------------------------
template<int NKT, bool FULL>
__global__ __attribute__((amdgpu_waves_per_eu(4, 4))) __launch_bounds__(256)
void attn(const bf16* __restrict__ Qb, const bf16* __restrict__ Kb,
          const bf16* __restrict__ Vtb, bf16* __restrict__ Cat,
          bf16* __restrict__ Opart, float* __restrict__ lpart)
{
    const int m0 = blockIdx.x * 128;
    const int h  = blockIdx.y;
    const int half = blockIdx.z;
    const int keybase = half * (NKT * 64);

    __shared__ __align__(16) bf16 ka[2][64 * 64];   // 8 KB/buf, swizzled [key][dk]
    __shared__ __align__(16) bf16 vt[2][64 * 64];   // 8 KB/buf, swizzled [dv][key]

    const int t = threadIdx.x, lane = t & 63, w = t >> 6;
    const int l15 = lane & 15, quad = lane >> 4;

    auto stage_kv = [&](int buf, int key0) {
        const char* kg = (const char*)(Kb + ((size_t)h * S_ + key0) * 64);
        #pragma unroll
        for (int j = 0; j < 2; j++) {
            int c = (j * 4 + w) * 64 + lane;
            int row = c >> 3, ch = (c & 7) ^ (row & 7);
            stage16(kg + row * 128 + ch * 16, (char*)&ka[buf][0] + (j * 4 + w) * 1024);
        }
        const char* vg = (const char*)(Vtb + (size_t)h * 64 * S_ + key0);
        #pragma unroll
        for (int j = 0; j < 2; j++) {
            int c = (j * 4 + w) * 64 + lane;
            int row = c >> 3, ch = (c & 7) ^ (row & 7);
            stage16(vg + (size_t)row * (S_ * 2) + ch * 16, (char*)&vt[buf][0] + (j * 4 + w) * 1024);
        }
    };

    // Q fragments, loop-invariant, straight from global (B-side of K·Qᵀ)
    bf16x8 qf[2][2];
    #pragma unroll
    for (int nq = 0; nq < 2; nq++)
        #pragma unroll
        for (int ks = 0; ks < 2; ks++)
            qf[nq][ks] = *(const bf16x8*)(Qb +
                ((size_t)h * S_ + m0 + w * 32 + nq * 16 + l15) * 64 + ks * 32 + quad * 8);

    const floatx4 fz = {0.f, 0.f, 0.f, 0.f};
    floatx4 acc[2][4];          // acc[nq][nt]: Oᵀ[dv=nt*16+quad*4+r][q=l15 of nq-tile]
    float rs[2] = {0.f, 0.f};
    #pragma unroll
    for (int nq = 0; nq < 2; nq++)
        #pragma unroll
        for (int nt = 0; nt < 4; nt++) acc[nq][nt] = fz;

    stage_kv(0, keybase);
    __syncthreads();

    for (int kt = 0; kt < NKT; kt++) {
        const int cur = kt & 1;
        if (kt + 1 < NKT) stage_kv(cur ^ 1, keybase + (kt + 1) * 64);

        // Sᵀ[key][q] = K·Qᵀ
        floatx4 sc[4][2];
        #pragma unroll
        for (int mk = 0; mk < 4; mk++)
            #pragma unroll
            for (int nq = 0; nq < 2; nq++) sc[mk][nq] = fz;
        #pragma unroll
        for (int ks = 0; ks < 2; ks++) {
            bf16x8 af[4];
            #pragma unroll
            for (int mk = 0; mk < 4; mk++)
                af[mk] = ldsfrag(&ka[cur][0], mk * 16 + l15, ks * 4 + quad);
            #pragma unroll
            for (int mk = 0; mk < 4; mk++)
                #pragma unroll
                for (int nq = 0; nq < 2; nq++)
                    sc[mk][nq] = MFMA16(af[mk], qf[nq][ks], sc[mk][nq]);
        }

        // p = exp2(s) in registers; per-lane partial row sums;
        // TRUNCATING one-instruction packs (v_perm_b32)
        union bf4u { bf16x4 v; unsigned int u[2]; };
        bf4u pf[4][2];
        #pragma unroll
        for (int mk = 0; mk < 4; mk++)
            #pragma unroll
            for (int nq = 0; nq < 2; nq++) {
                float p0 = EXP2(sc[mk][nq][0]);
                float p1 = EXP2(sc[mk][nq][1]);
                float p2 = EXP2(sc[mk][nq][2]);
                float p3 = EXP2(sc[mk][nq][3]);
                rs[nq] += (p0 + p1) + (p2 + p3);
                pf[mk][nq].u[0] = pktrunc(p0, p1);
                pf[mk][nq].u[1] = pktrunc(p2, p3);
            }

        // Oᵀ += Vᵀ·Pᵀ : per pair p of 16-key groups (32 keys per MFMA)
        #pragma unroll
        for (int p = 0; p < 2; p++) {
            union { bf16x8 v8; bf16x4 v4[2]; } b8[2];
            #pragma unroll
            for (int nq = 0; nq < 2; nq++) {
                b8[nq].v4[0] = pf[2 * p + 0][nq].v;
                b8[nq].v4[1] = pf[2 * p + 1][nq].v;
            }
            #pragma unroll
            for (int nt = 0; nt < 4; nt++) {
                const char* vb = (const char*)&vt[cur][0]
                               + (nt * 16 + l15) * 128 + (quad & 1) * 8;
                const int r7 = l15 & 7;            // row&7 for swizzle
                union { bf16x8 v8; bf16x4 v4[2]; } a8;
                a8.v4[0] = *(const bf16x4*)(vb + (((4 * p +     (quad >> 1)) ^ r7) << 4));
                a8.v4[1] = *(const bf16x4*)(vb + (((4 * p + 2 + (quad >> 1)) ^ r7) << 4));
                #pragma unroll
                for (int nq = 0; nq < 2; nq++)
                    acc[nq][nt] = MFMA16(a8.v8, b8[nq].v8, acc[nq][nt]);
            }
        }
        __syncthreads();   // staging(next) landed; all waves done with cur
    }

    // full row sums: q = l15, reduce across the 4 quads (lanes ±16, ±32)
    #pragma unroll
    for (int nq = 0; nq < 2; nq++) {
        rs[nq] += __shfl_xor(rs[nq], 16);
        rs[nq] += __shfl_xor(rs[nq], 32);
    }

    if (FULL) {
        #pragma unroll
        for (int nq = 0; nq < 2; nq++) {
            float inv = 1.0f / rs[nq];
            int q = m0 + w * 32 + nq * 16 + l15;
            #pragma unroll
            for (int nt = 0; nt < 4; nt++) {
                uint2 o;
                o.x = pktrunc(acc[nq][nt][0] * inv, acc[nq][nt][1] * inv);
                o.y = pktrunc(acc[nq][nt][2] * inv, acc[nq][nt][3] * inv);
                *(uint2*)(Cat + (size_t)q * (H_ * DV_) + h * 64 + nt * 16 + quad * 4) = o;
            }
        }
    } else {
        const size_t plane = (size_t)(half * H_ + h) * S_;
        #pragma unroll
        for (int nq = 0; nq < 2; nq++) {
            int q = m0 + w * 32 + nq * 16 + l15;
            #pragma unroll
            for (int nt = 0; nt < 4; nt++) {
                uint2 o;
                o.x = pktrunc(acc[nq][nt][0], acc[nq][nt][1]);
                o.y = pktrunc(acc[nq][nt][2], acc[nq][nt][3]);
                *(uint2*)(Opart + (plane + q) * 64 + nt * 16 + quad * 4) = o;
            }
            if (quad == 0) lpart[plane + q] = rs[nq];
        }
    }
}

// ---------------------------------------------------------------------------
// Kernel 2b: combine bf16 key-split partials -> Cat bf16
// ---------------------------------------------------------------------------
__global__ __launch_bounds__(256)
void combine(const bf16* __restrict__ Opart, const float* __restrict__ lpart,
             bf16* __restrict__ Cat)
{
    const int h = blockIdx.y;
    const int off = (blockIdx.x * 256 + threadIdx.x) * 8;   // within [S*64]
    const int s = off >> 6, dv = off & 63;
    union { bf16x8 v; bf16 e[8]; } o0, o1;
    o0.v = *(const bf16x8*)(Opart + (size_t)h * S_ * 64 + off);
    o1.v = *(const bf16x8*)(Opart + (size_t)(H_ + h) * S_ * 64 + off);
    float inv = 1.0f / (lpart[(size_t)h * S_ + s] + lpart[(size_t)(H_ + h) * S_ + s]);
    uint4 o;
    o.x = pktrunc((bf2f(o0.e[0]) + bf2f(o1.e[0])) * inv, (bf2f(o0.e[1]) + bf2f(o1.e[1])) * inv);
    o.y = pktrunc((bf2f(o0.e[2]) + bf2f(o1.e[2])) * inv, (bf2f(o0.e[3]) + bf2f(o1.e[3])) * inv);
    o.z = pktrunc((bf2f(o0.e[4]) + bf2f(o1.e[4])) * inv, (bf2f(o0.e[5]) + bf2f(o1.e[5])) * inv);
    o.w = pktrunc((bf2f(o0.e[6]) + bf2f(o1.e[6])) * inv, (bf2f(o0.e[7]) + bf2f(o1.e[7])) * inv);
    *(uint4*)(Cat + (size_t)s * (H_ * DV_) + h * 64 + dv) = o;
}

// ---------------------------------------------------------------------------
// Kernel 3: output projection, 128x64 tiles, BK=32, dbuf staging. LDS 24 KB.
// ---------------------------------------------------------------------------
__global__ __launch_bounds__(256)
void out_proj(const bf16* __restrict__ Cat, const bf16* __restrict__ Wct,
              const float* __restrict__ bc, float* __restrict__ out)
{
    const int m0 = blockIdx.x * 128;
    const int n0 = blockIdx.y * 64;
    __shared__ __align__(16) bf16 ca[2][128 * 32];   // 8 KB/buf
    __shared__ __align__(16) bf16 wb2[2][64 * 32];   // 4 KB/buf

    const int t = threadIdx.x, lane = t & 63, w = t >> 6;
    const int l15 = lane & 15, quad = lane >> 4;

    auto stage_a = [&](int buf, int kk) {
        #pragma unroll
        for (int j = 0; j < 2; j++) {
            int row = j * 64 + (t >> 2);
            int ch  = (t & 3) ^ (row & 3);
            stage16((const char*)Cat + ((size_t)(m0 + row) * D_ + kk) * 2 + ch * 16,
                    (char*)&ca[buf][0] + (j * 4 + w) * 1024);
        }
    };
    auto stage_b = [&](int buf, int kk) {
        int row = t >> 2;                   // 0..63
        int ch  = (t & 3) ^ (row & 3);
        stage16((const char*)Wct + ((size_t)(n0 + row) * D_ + kk) * 2 + ch * 16,
                (char*)&wb2[buf][0] + w * 1024);
    };

    const floatx4 fz = {0.f, 0.f, 0.f, 0.f};
    floatx4 acc[2][4];
    #pragma unroll
    for (int mt = 0; mt < 2; mt++)
        #pragma unroll
        for (int nt = 0; nt < 4; nt++) acc[mt][nt] = fz;

    stage_a(0, 0); stage_b(0, 0);
    for (int kt = 0; kt < 32; kt++) {
        int cur = kt & 1;
        __syncthreads();
        if (kt < 31) { stage_a(cur ^ 1, (kt + 1) * 32); stage_b(cur ^ 1, (kt + 1) * 32); }
        bf16x8 a0 = ldsfrag32(&ca[cur][0], w * 32 + l15,      quad);
        bf16x8 a1 = ldsfrag32(&ca[cur][0], w * 32 + 16 + l15, quad);
        #pragma unroll
        for (int nt = 0; nt < 4; nt++) {
            bf16x8 b = ldsfrag32(&wb2[cur][0], nt * 16 + l15, quad);
            acc[0][nt] = MFMA16(a0, b, acc[0][nt]);
            acc[1][nt] = MFMA16(a1, b, acc[1][nt]);
        }
    }

    #pragma unroll
    for (int nt = 0; nt < 4; nt++) {
        int col = n0 + nt * 16 + l15;
        float bias = bc[col];
        #pragma unroll
        for (int mt = 0; mt < 2; mt++)
            #pragma unroll
            for (int r = 0; r < 4; r++) {
                int row = m0 + w * 32 + mt * 16 + quad * 4 + r;
                out[(size_t)row * D_ + col] = acc[mt][nt][r] + bias;
            }
    }
}

extern "C" void kernel_launch(void* const* d_in, const int* in_sizes, int n_in,
                              void* d_out, int out_size, void* d_ws, size_t ws_size,
                              hipStream_t stream)
{
    const float* x  = (const float*)d_in[0];
    const float* Wq = (const float*)d_in[1];
    const float* Wk = (const float*)d_in[2];
    const float* Wv = (const float*)d_in[3];
    const float* Wc = (const float*)d_in[4];
    const float* bc = (const float*)d_in[5];
    float* out = (float*)d_out;

    bf16* xb  = (bf16*)d_ws;                          // [S][D] 8MB, aliased as Cat
    bf16* Cat = xb;
    bf16* Wt  = xb  + (size_t)S_ * D_;                // [3072][1024] 6MB
    bf16* Wct = Wt  + (size_t)3 * H_ * 64 * D_;       // [1024][1024] 2MB
    bf16* Qb  = Wct + (size_t)D_ * H_ * DV_;          // [H][S][64]  8MB
    bf16* Kb  = Qb  + (size_t)H_ * S_ * 64;           // [H][S][64]  8MB
    bf16* Vtb = Kb  + (size_t)H_ * S_ * 64;           // [H][64][S]  8MB
    bf16* Opart = Vtb + (size_t)H_ * 64 * S_;         // [2][H][S][64] bf16 16MB
    float* lpart = (float*)(Opart + (size_t)2 * H_ * S_ * 64);  // [2][H][S] 512KB

    const size_t need_split = (size_t)((char*)(lpart + (size_t)2 * H_ * S_) - (char*)d_ws);
    const bool split = ws_size >= need_split;

    prep<<<dim3(3072), 256, 0, stream>>>(x, Wq, Wk, Wv, Wc, xb, Wt, Wct);
    qkv_gemm<<<dim3(S_ / 128, 3072 / 128), 256, 0, stream>>>(xb, Wt, Qb, Kb, Vtb);

    if (split) {
        attn<32, false><<<dim3(S_ / 128, H_, 2), 256, 0, stream>>>(
            Qb, Kb, Vtb, Cat, Opart, lpart);
        combine<<<dim3(S_ * 64 / 2048, H_), 256, 0, stream>>>(Opart, lpart, Cat);
    } else {
        attn<64, true><<<dim3(S_ / 128, H_, 1), 256, 0, stream>>>(
            Qb, Kb, Vtb, Cat, Opart, lpart);
    }

    out_proj<<<dim3(S_ / 128, D_ / 64), 256, 0, stream>>>(Cat, Wct, bc, out);
}